// Round 2
// baseline (290.676 us; speedup 1.0000x reference)
//
#include <hip/hip_runtime.h>

#define BATCH   8192
#define FEAT    256
#define NCLASS  100000
#define ALPHA_C 1.0f
#define EPS_C   1e-6f

// total new_centers elements
#define NC_ELEMS (NCLASS * FEAT)          // 25,600,000
// d_out float4 vectors covering d_out[0 .. 25,600,000)
#define NVEC (NC_ELEMS / 4)               // 6,400,000
#define COPY_BLOCKS (NVEC / 256)          // 25,000

// Copy centers -> d_out shifted by +1 float (d_out[0] is the loss slot,
// zeroed here by the v==0 lane). Aligned float4 load from centers, shift via
// __shfl_up within the wave, aligned float4 store to d_out.
// Blocks 0..31 additionally compute the per-class counts (8192 atomics) --
// stream-ordered after the memset of counts, before the scatter kernel.
__global__ void copy_count_kernel(const float* __restrict__ centers,
                                  float* __restrict__ out /* = d_out base */,
                                  const int* __restrict__ target,
                                  int* __restrict__ counts) {
    int v = blockIdx.x * blockDim.x + threadIdx.x;   // [0, NVEC)
    const float4* cvec = (const float4*)centers;
    float4 cv = cvec[v];                             // centers[4v .. 4v+3]
    int lane = threadIdx.x & 63;
    float prev = __shfl_up(cv.w, 1);                 // lane-1's c[4(v-1)+3] = c[4v-1]
    if (lane == 0) {
        prev = (v > 0) ? centers[4 * v - 1] : 0.0f;  // v==0: out[0]=0 (loss accumulator)
    }
    float4 ov;
    ov.x = prev; ov.y = cv.x; ov.z = cv.y; ov.w = cv.z;
    ((float4*)out)[v] = ov;
    if (v == 0) out[NC_ELEMS] = centers[NC_ELEMS - 1];  // tail element

    // fused per-class count: first 32 blocks cover the 8192 samples
    if (blockIdx.x < (BATCH / 256)) {
        int b = blockIdx.x * 256 + threadIdx.x;
        atomicAdd(&counts[target[b]], 1);
    }
}

// One block per sample; 256 threads = FEAT.
// Scatter update into out1 (= d_out+1) and accumulate scaled loss into out0.
__global__ void scatter_kernel(const float* __restrict__ features,
                               const int* __restrict__ target,
                               const float* __restrict__ centers,
                               const int* __restrict__ counts,
                               float* __restrict__ out /* d_out base */) {
    int b = blockIdx.x;
    int d = threadIdx.x;
    int t = target[b];
    float c = centers[t * FEAT + d];
    float f = features[b * FEAT + d];
    float diff = c - f;

    // loss partial: block-reduce diff^2, atomic-add pre-scaled into out[0]
    float sq = diff * diff;
    #pragma unroll
    for (int off = 32; off > 0; off >>= 1) sq += __shfl_down(sq, off, 64);
    __shared__ float red[4];
    int wave = threadIdx.x >> 6;
    int lane = threadIdx.x & 63;
    if (lane == 0) red[wave] = sq;
    __syncthreads();
    if (threadIdx.x == 0) {
        float blocksum = red[0] + red[1] + red[2] + red[3];
        atomicAdd(&out[0], blocksum * (1.0f / (float)(BATCH * FEAT)));
    }

    // scatter update: new_centers -= alpha*diff/(count+eps), accumulated per class
    float inv = ALPHA_C / ((float)counts[t] + EPS_C);
    atomicAdd(&out[1 + t * FEAT + d], -diff * inv);
}

extern "C" void kernel_launch(void* const* d_in, const int* in_sizes, int n_in,
                              void* d_out, int out_size, void* d_ws, size_t ws_size,
                              hipStream_t stream) {
    const float* features = (const float*)d_in[0];
    const int*   target   = (const int*)d_in[1];
    const float* centers  = (const float*)d_in[2];
    float* out = (float*)d_out;

    int* counts = (int*)d_ws;   // 100000 ints

    hipMemsetAsync(counts, 0, NCLASS * sizeof(int), stream);
    copy_count_kernel<<<COPY_BLOCKS, 256, 0, stream>>>(centers, out, target, counts);
    scatter_kernel<<<BATCH, FEAT, 0, stream>>>(features, target, centers, counts, out);
}